// Round 2
// baseline (1023.930 us; speedup 1.0000x reference)
//
#include <hip/hip_runtime.h>
#include <stdint.h>

#define S_ 2048
#define R_ 512
#define C_ 64
#define HC_ 128

typedef unsigned short u16;
typedef __attribute__((ext_vector_type(8))) short bf8_t;   // 8 bf16 (4 VGPRs)
typedef __attribute__((ext_vector_type(4))) float f4_t;    // 4 fp32 acc

__device__ __forceinline__ u16 f2b(float f) {  // f32 -> bf16 RNE
    union { float f; unsigned int i; } x; x.f = f;
    unsigned int r = x.i + 0x7fffu + ((x.i >> 16) & 1u);
    return (u16)(r >> 16);
}
__device__ __forceinline__ float b2f(u16 u) {
    union { unsigned int i; float f; } x; x.i = ((unsigned int)u) << 16; return x.f;
}
__device__ __forceinline__ unsigned int pack2(float a, float b) {
    return (unsigned int)f2b(a) | ((unsigned int)f2b(b) << 16);
}
__device__ __forceinline__ void u4_to_f8(uint4 p, float* f) {  // 8 bf16 -> 8 f32
    union { unsigned int i; float f; } x;
    x.i = p.x << 16;         f[0] = x.f;
    x.i = p.x & 0xffff0000u; f[1] = x.f;
    x.i = p.y << 16;         f[2] = x.f;
    x.i = p.y & 0xffff0000u; f[3] = x.f;
    x.i = p.z << 16;         f[4] = x.f;
    x.i = p.z & 0xffff0000u; f[5] = x.f;
    x.i = p.w << 16;         f[6] = x.f;
    x.i = p.w & 0xffff0000u; f[7] = x.f;
}

// ---------------- K1a: LN + qsum + (k,v) = mn @ [Wk|Wv] via MFMA ----------------
// grid: 32768 blocks (512 r x 64 s-chunks of 32 tokens), 256 threads
__global__ __launch_bounds__(256) void k1a(
    const float* __restrict__ m, const float* __restrict__ mask,
    const float* __restrict__ lnw_g, const float* __restrict__ lnb_g,
    const float* __restrict__ Wk, const float* __restrict__ Wv,
    u16* __restrict__ kbuf, u16* __restrict__ vbuf,
    float* __restrict__ qsum, float* __restrict__ msum)
{
    __shared__ __attribute__((aligned(16))) u16 mns[32 * 72];   // [tok][c] bf16, pitch 72
    __shared__ __attribute__((aligned(16))) u16 kvT[32 * 72];   // [n=(k0..15,v0..15)][c] bf16
    __shared__ __attribute__((aligned(16))) u16 kva[32 * 40];   // D staging [tok][32] bf16
    __shared__ float qred[4][64];
    __shared__ float msred[4];

    const int tid = threadIdx.x;
    const int bi  = blockIdx.x;
    const int r   = bi >> 6;
    const int s0  = (bi & 63) << 5;

    // stage B^T as bf16: kvT[j][c] = j<16 ? Wk[c][j] : Wv[c][j-16]
    for (int idx = tid; idx < 2048; idx += 256) {
        int j = idx & 31, c = idx >> 5;
        float w = (j < 16) ? Wk[c * 16 + j] : Wv[c * 16 + (j - 16)];
        kvT[j * 72 + c] = f2b(w);
    }

    const int g = tid >> 4, l = tid & 15;
    const float4 lw4 = *(const float4*)&lnw_g[4 * l];
    const float4 lb4 = *(const float4*)&lnb_g[4 * l];

    float4 qacc = {0.f, 0.f, 0.f, 0.f};
    float msacc = 0.f;
    #pragma unroll
    for (int tt = 0; tt < 2; ++tt) {
        int t = g + tt * 16;
        int s = s0 + t;
        size_t base = ((size_t)s * R_ + r) * C_;
        float4 x = *(const float4*)&m[base + 4 * l];
        float sum = x.x + x.y + x.z + x.w;
        float ssq = x.x * x.x + x.y * x.y + x.z * x.z + x.w * x.w;
        #pragma unroll
        for (int off = 1; off <= 8; off <<= 1) {
            sum += __shfl_xor(sum, off);
            ssq += __shfl_xor(ssq, off);
        }
        float mu  = sum * (1.f / 64.f);
        float var = ssq * (1.f / 64.f) - mu * mu;
        float rs  = rsqrtf(var + 1e-5f);
        float4 mn;
        mn.x = (x.x - mu) * rs * lw4.x + lb4.x;
        mn.y = (x.y - mu) * rs * lw4.y + lb4.y;
        mn.z = (x.z - mu) * rs * lw4.z + lb4.z;
        mn.w = (x.w - mu) * rs * lw4.w + lb4.w;
        float mk = mask[(size_t)s * R_ + r];
        qacc.x += mn.x * mk; qacc.y += mn.y * mk;
        qacc.z += mn.z * mk; qacc.w += mn.w * mk;
        if (l == 0) msacc += mk;
        uint2 p; p.x = pack2(mn.x, mn.y); p.y = pack2(mn.z, mn.w);
        *(uint2*)&mns[t * 72 + 4 * l] = p;
    }
    // reduce qacc across the 4 groups of each wave
    qacc.x += __shfl_xor(qacc.x, 16); qacc.y += __shfl_xor(qacc.y, 16);
    qacc.z += __shfl_xor(qacc.z, 16); qacc.w += __shfl_xor(qacc.w, 16);
    qacc.x += __shfl_xor(qacc.x, 32); qacc.y += __shfl_xor(qacc.y, 32);
    qacc.z += __shfl_xor(qacc.z, 32); qacc.w += __shfl_xor(qacc.w, 32);
    msacc += __shfl_xor(msacc, 16);  msacc += __shfl_xor(msacc, 32);
    const int wv = tid >> 6, lane = tid & 63;
    if (lane < 16) *(float4*)&qred[wv][4 * lane] = qacc;
    if (lane == 0) msred[wv] = msacc;
    __syncthreads();

    // MFMA: wave wv -> tile (mt = wv&1, nt = wv>>1); K=64 in 2 steps
    {
        const int mt = wv & 1, nt = wv >> 1;
        const int r16 = lane & 15, quad = lane >> 4;
        f4_t acc = {0.f, 0.f, 0.f, 0.f};
        #pragma unroll
        for (int kt = 0; kt < 2; ++kt) {
            bf8_t a = *(const bf8_t*)&mns[(mt * 16 + r16) * 72 + kt * 32 + quad * 8];
            bf8_t b = *(const bf8_t*)&kvT[(nt * 16 + r16) * 72 + kt * 32 + quad * 8];
            acc = __builtin_amdgcn_mfma_f32_16x16x32_bf16(a, b, acc, 0, 0, 0);
        }
        #pragma unroll
        for (int i = 0; i < 4; ++i) {
            int row = mt * 16 + quad * 4 + i;
            kva[row * 40 + nt * 16 + r16] = f2b(acc[i]);
        }
    }
    __syncthreads();

    // coalesced copy to kbuf/vbuf + qsum/msum atomics
    for (int uidx = tid; uidx < 512; uidx += 256) {
        int t = uidx >> 4, u = uidx & 15;
        unsigned int val = *(const unsigned int*)&kva[t * 40 + u * 2];
        int s = s0 + t;
        size_t tb = ((size_t)r * S_ + s) * 16;
        if (u < 8) *(unsigned int*)&kbuf[tb + u * 2] = val;
        else       *(unsigned int*)&vbuf[tb + (u - 8) * 2] = val;
    }
    if (tid < 64) {
        float tot = qred[0][tid] + qred[1][tid] + qred[2][tid] + qred[3][tid];
        atomicAdd(&qsum[r * 64 + tid], tot);
    }
    if (tid == 0) atomicAdd(&msum[r], msred[0] + msred[1] + msred[2] + msred[3]);
}

// ---------------- K1b: q + global-softmax pooled attention -> opool ----------------
// grid: 512 blocks (one per r), 256 threads (wave w -> heads w and w+4)
__global__ __launch_bounds__(256) void k1b(
    const float* __restrict__ qsum, const float* __restrict__ msum,
    const float* __restrict__ Wq, const float* __restrict__ mask,
    const u16* __restrict__ kbuf, const u16* __restrict__ vbuf,
    float* __restrict__ opool)
{
    __shared__ float qbar[64];
    __shared__ float qh[128];
    const int tid = threadIdx.x;
    const int r   = blockIdx.x;

    if (tid < 64) qbar[tid] = qsum[r * 64 + tid] / (msum[r] + 1e-10f);
    __syncthreads();
    if (tid < 128) {
        float a = 0.f;
        #pragma unroll 8
        for (int c = 0; c < 64; ++c) a += qbar[c] * Wq[c * 128 + tid];
        qh[tid] = a * 0.25f;   // CH^-0.5
    }
    __syncthreads();

    const int wv = tid >> 6, lane = tid & 63;
    const int h0 = wv, h1 = wv + 4;
    float qa[16], qb[16];
    #pragma unroll
    for (int ch = 0; ch < 16; ++ch) { qa[ch] = qh[h0 * 16 + ch]; qb[ch] = qh[h1 * 16 + ch]; }

    // sweep 1: max
    float m0 = -1e30f, m1 = -1e30f;
    for (int i = 0; i < 32; ++i) {
        int s = i * 64 + lane;
        size_t tb = ((size_t)r * S_ + s) * 16;
        float kf[16];
        u4_to_f8(*(const uint4*)&kbuf[tb], kf);
        u4_to_f8(*(const uint4*)&kbuf[tb + 8], kf + 8);
        float bias = (mask[(size_t)s * R_ + r] - 1.f) * 1e9f;
        float a0 = bias, a1 = bias;
        #pragma unroll
        for (int ch = 0; ch < 16; ++ch) { a0 += qa[ch] * kf[ch]; a1 += qb[ch] * kf[ch]; }
        m0 = fmaxf(m0, a0); m1 = fmaxf(m1, a1);
    }
    #pragma unroll
    for (int off = 1; off < 64; off <<= 1) {
        m0 = fmaxf(m0, __shfl_xor(m0, off));
        m1 = fmaxf(m1, __shfl_xor(m1, off));
    }
    // sweep 2: sum + weighted V
    float l0 = 0.f, l1 = 0.f;
    float o0[16], o1[16];
    #pragma unroll
    for (int ch = 0; ch < 16; ++ch) { o0[ch] = 0.f; o1[ch] = 0.f; }
    for (int i = 0; i < 32; ++i) {
        int s = i * 64 + lane;
        size_t tb = ((size_t)r * S_ + s) * 16;
        float kf[16], vf[16];
        u4_to_f8(*(const uint4*)&kbuf[tb], kf);
        u4_to_f8(*(const uint4*)&kbuf[tb + 8], kf + 8);
        u4_to_f8(*(const uint4*)&vbuf[tb], vf);
        u4_to_f8(*(const uint4*)&vbuf[tb + 8], vf + 8);
        float bias = (mask[(size_t)s * R_ + r] - 1.f) * 1e9f;
        float a0 = bias, a1 = bias;
        #pragma unroll
        for (int ch = 0; ch < 16; ++ch) { a0 += qa[ch] * kf[ch]; a1 += qb[ch] * kf[ch]; }
        float w0 = expf(a0 - m0), w1 = expf(a1 - m1);
        l0 += w0; l1 += w1;
        #pragma unroll
        for (int ch = 0; ch < 16; ++ch) { o0[ch] += w0 * vf[ch]; o1[ch] += w1 * vf[ch]; }
    }
    #pragma unroll
    for (int off = 1; off < 64; off <<= 1) {
        l0 += __shfl_xor(l0, off); l1 += __shfl_xor(l1, off);
        #pragma unroll
        for (int ch = 0; ch < 16; ++ch) {
            o0[ch] += __shfl_xor(o0[ch], off);
            o1[ch] += __shfl_xor(o1[ch], off);
        }
    }
    if (lane == 0) {
        float inv0 = 1.f / l0, inv1 = 1.f / l1;
        #pragma unroll
        for (int ch = 0; ch < 16; ++ch) {
            opool[r * 128 + h0 * 16 + ch] = o0[ch] * inv0;
            opool[r * 128 + h1 * 16 + ch] = o1[ch] * inv1;
        }
    }
}

// ---------------- K2: LN + g=sigmoid(mn@Wg+bg), out = (opool*g)@Wo + bo ----------------
// grid: 32768 blocks (512 r x 64 s-chunks of 32 tokens), 256 threads
__global__ __launch_bounds__(256) void k2(
    const float* __restrict__ m,
    const float* __restrict__ lnw_g, const float* __restrict__ lnb_g,
    const float* __restrict__ Wg, const float* __restrict__ bg,
    const float* __restrict__ Wo, const float* __restrict__ bo,
    const float* __restrict__ opool, float* __restrict__ out)
{
    __shared__ __attribute__((aligned(16))) u16 WgT[128 * 72];   // [hc][c] bf16
    __shared__ __attribute__((aligned(16))) u16 WoT[64 * 136];   // [c][hc] bf16
    __shared__ __attribute__((aligned(16))) u16 mns[32 * 72];    // [tok][c] bf16
    __shared__ __attribute__((aligned(16))) u16 olds[32 * 136];  // [tok][hc] bf16
    __shared__ __attribute__((aligned(16))) float outs[32 * 68]; // [tok][c] f32
    __shared__ float opl[128], bgl[128];
    __shared__ float bol[64];

    const int tid = threadIdx.x;
    const int bi  = blockIdx.x;
    const int r   = bi >> 6;
    const int s0  = (bi & 63) << 5;

    for (int idx = tid; idx < 8192; idx += 256) {
        int c = idx >> 7, hc = idx & 127;
        WgT[hc * 72 + c] = f2b(Wg[idx]);      // Wg[c][hc] -> WgT[hc][c]
    }
    for (int idx = tid; idx < 8192; idx += 256) {
        int hc = idx >> 6, c = idx & 63;
        WoT[c * 136 + hc] = f2b(Wo[idx]);     // Wo[hc][c] -> WoT[c][hc]
    }
    if (tid < 128) { opl[tid] = opool[r * 128 + tid]; bgl[tid] = bg[tid]; }
    if (tid < 64)  { bol[tid] = bo[tid]; }

    const int g = tid >> 4, l = tid & 15;
    const float4 lw4 = *(const float4*)&lnw_g[4 * l];
    const float4 lb4 = *(const float4*)&lnb_g[4 * l];
    #pragma unroll
    for (int tt = 0; tt < 2; ++tt) {
        int t = g + tt * 16;
        int s = s0 + t;
        size_t base = ((size_t)s * R_ + r) * C_;
        float4 x = *(const float4*)&m[base + 4 * l];
        float sum = x.x + x.y + x.z + x.w;
        float ssq = x.x * x.x + x.y * x.y + x.z * x.z + x.w * x.w;
        #pragma unroll
        for (int off = 1; off <= 8; off <<= 1) {
            sum += __shfl_xor(sum, off);
            ssq += __shfl_xor(ssq, off);
        }
        float mu  = sum * (1.f / 64.f);
        float var = ssq * (1.f / 64.f) - mu * mu;
        float rs  = rsqrtf(var + 1e-5f);
        uint2 p;
        p.x = pack2((x.x - mu) * rs * lw4.x + lb4.x, (x.y - mu) * rs * lw4.y + lb4.y);
        p.y = pack2((x.z - mu) * rs * lw4.z + lb4.z, (x.w - mu) * rs * lw4.w + lb4.w);
        *(uint2*)&mns[t * 72 + 4 * l] = p;
    }
    __syncthreads();

    const int wv = tid >> 6, lane = tid & 63;
    const int r16 = lane & 15, quad = lane >> 4;

    // step 2: z = mns[32x64] @ Wg[64x128]; 16 tiles, 4 per wave
    #pragma unroll
    for (int i = 0; i < 4; ++i) {
        int id = wv * 4 + i;
        int mt = id >> 3, nt = id & 7;
        f4_t acc = {0.f, 0.f, 0.f, 0.f};
        #pragma unroll
        for (int kt = 0; kt < 2; ++kt) {
            bf8_t a = *(const bf8_t*)&mns[(mt * 16 + r16) * 72 + kt * 32 + quad * 8];
            bf8_t b = *(const bf8_t*)&WgT[(nt * 16 + r16) * 72 + kt * 32 + quad * 8];
            acc = __builtin_amdgcn_mfma_f32_16x16x32_bf16(a, b, acc, 0, 0, 0);
        }
        int hc = nt * 16 + r16;
        float og = opl[hc], bgv = bgl[hc];
        #pragma unroll
        for (int ii = 0; ii < 4; ++ii) {
            int row = mt * 16 + quad * 4 + ii;
            float z  = acc[ii] + bgv;
            float gv = 1.f / (1.f + expf(-z));
            olds[row * 136 + hc] = f2b(og * gv);
        }
    }
    __syncthreads();

    // step 3: out = o[32x128] @ Wo[128x64]; 8 tiles, 2 per wave
    #pragma unroll
    for (int i = 0; i < 2; ++i) {
        int id = wv * 2 + i;
        int mt = id >> 2, nt = id & 3;
        f4_t acc = {0.f, 0.f, 0.f, 0.f};
        #pragma unroll
        for (int kt = 0; kt < 4; ++kt) {
            bf8_t a = *(const bf8_t*)&olds[(mt * 16 + r16) * 136 + kt * 32 + quad * 8];
            bf8_t b = *(const bf8_t*)&WoT[(nt * 16 + r16) * 136 + kt * 32 + quad * 8];
            acc = __builtin_amdgcn_mfma_f32_16x16x32_bf16(a, b, acc, 0, 0, 0);
        }
        int c = nt * 16 + r16;
        float bov = bol[c];
        #pragma unroll
        for (int ii = 0; ii < 4; ++ii) {
            int row = mt * 16 + quad * 4 + ii;
            outs[row * 68 + c] = acc[ii] + bov;
        }
    }
    __syncthreads();

    // coalesced f32 store: out[s][r][c]
    #pragma unroll
    for (int tt = 0; tt < 2; ++tt) {
        int t = g + tt * 16;
        int s = s0 + t;
        size_t base = ((size_t)s * R_ + r) * C_;
        *(float4*)&out[base + 4 * l] = *(const float4*)&outs[t * 68 + 4 * l];
    }
}

extern "C" void kernel_launch(void* const* d_in, const int* in_sizes, int n_in,
                              void* d_out, int out_size, void* d_ws, size_t ws_size,
                              hipStream_t stream)
{
    const float* m    = (const float*)d_in[0];
    const float* mask = (const float*)d_in[1];
    const float* lnw  = (const float*)d_in[2];
    const float* lnb  = (const float*)d_in[3];
    const float* Wq   = (const float*)d_in[4];
    const float* Wk   = (const float*)d_in[5];
    const float* Wv   = (const float*)d_in[6];
    const float* Wg   = (const float*)d_in[7];
    const float* bg   = (const float*)d_in[8];
    const float* Wo   = (const float*)d_in[9];
    const float* bo   = (const float*)d_in[10];
    float* out = (float*)d_out;

    char* ws = (char*)d_ws;
    u16*   kbuf  = (u16*)ws;                                   // 32 MB (bf16)
    u16*   vbuf  = (u16*)(ws + (size_t)33554432);              // 32 MB (bf16)
    float* qsum  = (float*)(ws + (size_t)67108864);            // 128 KB
    float* msum  = (float*)(ws + (size_t)67108864 + 131072);   // 2 KB
    float* opool = (float*)(ws + (size_t)67108864 + 131072 + 2048);  // 256 KB

    hipMemsetAsync(ws + (size_t)67108864, 0, 131072 + 2048, stream);
    k1a<<<32768, 256, 0, stream>>>(m, mask, lnw, lnb, Wk, Wv, kbuf, vbuf, qsum, msum);
    k1b<<<512, 256, 0, stream>>>(qsum, msum, Wq, mask, kbuf, vbuf, opool);
    k2<<<32768, 256, 0, stream>>>(m, lnw, lnb, Wg, bg, Wo, bo, opool, out);
}